// Round 6
// baseline (311.095 us; speedup 1.0000x reference)
//
#include <hip/hip_runtime.h>
#include <hip/hip_bf16.h>
#include <math.h>

// Problem constants
#define BPART   524288
#define NBLK    (BPART / 256)  // 2048 blocks x 256 particles (8 waves x 32)
#define W7_OFF  98304          // 6 * 16384 bf16
#define WB_N    102400         // + 32*128 (padded W7t), bf16 count
#define BIAS_N  800            // 6*128 + 32 floats
#define PREP_N  (WB_N + BIAS_N)

typedef __bf16 bf16x8 __attribute__((ext_vector_type(8)));
typedef float  f32x16 __attribute__((ext_vector_type(16)));
typedef float  f32x4  __attribute__((ext_vector_type(4)));
typedef float  f32x2  __attribute__((ext_vector_type(2)));
typedef unsigned u32x4 __attribute__((ext_vector_type(4)));

#define MFMA __builtin_amdgcn_mfma_f32_32x32x16_bf16
#define UNROLL _Pragma("unroll")

__device__ __forceinline__ unsigned short f2bf(float f) {
  union { float f; unsigned u; } v; v.f = f;
  unsigned r = v.u + 0x7fffu + ((v.u >> 16) & 1u);   // RNE
  return (unsigned short)(r >> 16);
}
// pack two fp32 -> bf16x2 (low16 = a, high16 = b), explicit RNE — verified.
// (v_cvt_pk_bf16_f32 regressed absmax 7.8e-3 -> 4.2e-2 in R4: not RNE. Do
// not substitute it.)
__device__ __forceinline__ unsigned pack_bf16(float a, float b) {
  unsigned ua = __builtin_bit_cast(unsigned, a) + 0x8000u;
  unsigned ub = __builtin_bit_cast(unsigned, b) + 0x8000u;
  return __builtin_amdgcn_perm(ub, ua, 0x07060302u);
}

// sigma: D-slot index -> real feature index. With weight rows (and biases)
// stored permuted by sigma, the MFMA D layout (n = 32tn+8q+4lk+j per lane)
// becomes, after pairwise bf16 packing, EXACTLY the next layer's B-fragment
// layout (k = 16t+8lk+4h+j, t=c>>1, h=c&1, c=4tn+q). Bijective bit shuffle.
__device__ __forceinline__ int sigma(int n) {
  int c = ((n >> 5) << 2) | ((n >> 3) & 3);
  return ((c >> 1) << 4) | (((n >> 2) & 1) << 3) | ((c & 1) << 2) | (n & 3);
}

// packed fp32 VALU (VOP3P)
__device__ __forceinline__ f32x2 pk_mul(f32x2 a, f32x2 b) {
  f32x2 d; asm("v_pk_mul_f32 %0, %1, %2" : "=v"(d) : "v"(a), "v"(b)); return d;
}
__device__ __forceinline__ f32x2 pk_fma(f32x2 a, f32x2 b, f32x2 c) {
  f32x2 d; asm("v_pk_fma_f32 %0, %1, %2, %3" : "=v"(d) : "v"(a), "v"(b), "v"(c)); return d;
}
// tanh-form GELU on a pair, DIVISION-FREE tail (R6):
//   y = z*(c0 + c1 z^2)            (log2-domain sigmoid argument)
//   e = 2^(-|y|) in (0,1]          (abs folds into v_exp_f32 modifier)
//   R(e) ~= 1/(1+e), deg-4 poly (Chebyshev-economized, |err|<1.6e-3;
//          sigma err = e*errR*, g err < 1e-4 -- below tanh-form intrinsic)
//   m = z*e*R = z*(1-sigma(|y|));  g = max(z-m, m)
//   (z>=0: g=z-m=z*sigma(y), and z-m>=m since e*R<=0.5;
//    z<0 : g=m=z*(1-sigma(|y|))=z*sigma(y), and z-m<=m. Branchless.)
// Replaces 2x v_rcp (quarter-rate) + 2 add + 2 mul with 4 pk_fma + 2 pk ops:
// transcendental ops per pair drop 4 -> 2.
__device__ __forceinline__ f32x2 gelu2(f32x2 z) {
  const f32x2 c1 = {0.1029432f, 0.1029432f};
  const f32x2 c0 = {2.30220818f, 2.30220818f};
  f32x2 z2 = pk_mul(z, z);
  f32x2 u  = pk_fma(z2, c1, c0);
  f32x2 y  = pk_mul(z, u);
  f32x2 e;
  e.x = __builtin_amdgcn_exp2f(-fabsf(y.x));
  e.y = __builtin_amdgcn_exp2f(-fabsf(y.y));
  const f32x2 a4 = { 0.131687f,  0.131687f};
  const f32x2 a3 = {-0.488342f, -0.488342f};
  const f32x2 a2 = { 0.831279f,  0.831279f};
  const f32x2 a1 = {-0.973596f, -0.973596f};
  const f32x2 a0 = { 0.998457f,  0.998457f};
  f32x2 R = pk_fma(e, a4, a3);
  R = pk_fma(e, R, a2);
  R = pk_fma(e, R, a1);
  R = pk_fma(e, R, a0);
  f32x2 m = pk_mul(z, pk_mul(e, R));
  const f32x2 mone = {-1.0f, -1.0f};
  f32x2 zm = pk_fma(m, mone, z);       // z - m
  f32x2 g;
  g.x = fmaxf(zm.x, m.x);
  g.y = fmaxf(zm.y, m.y);
  return g;
}
// async 16B global->LDS (lane-linear dest)
__device__ __forceinline__ void cp16(const void* g, void* l) {
  __builtin_amdgcn_global_load_lds(
      (const __attribute__((address_space(1))) void*)g,
      (__attribute__((address_space(3))) void*)l, 16, 0, 0);
}

// ---- prep: cast+transpose fp32 weights into d_ws as the EXACT swizzled
// LDS image, with rows sigma-permuted (see sigma()). Biases permuted too. ----
__global__ void prep_weights(
    const float* __restrict__ W1, const float* __restrict__ W2,
    const float* __restrict__ W3, const float* __restrict__ W4,
    const float* __restrict__ W5, const float* __restrict__ W6,
    const float* __restrict__ W7,
    const float* __restrict__ b1, const float* __restrict__ b2,
    const float* __restrict__ b3, const float* __restrict__ b4,
    const float* __restrict__ b5, const float* __restrict__ b6,
    const float* __restrict__ b7,
    unsigned short* __restrict__ wsb, float* __restrict__ wsf)
{
  int idx = blockIdx.x * 256 + threadIdx.x;
  if (idx < WB_N) {
    unsigned short v = 0;
    if (idx < W7_OFF) {                     // W1..W6: Wt[sigma(n)][k] swizzled
      int l = idx >> 14;
      int o = idx & 16383;
      int n = o >> 7, e = o & 127;
      int k = (((e >> 3) ^ (n & 7)) << 3) | (e & 7);
      int sn = sigma(n);
      const float* W = (l==0)?W1:(l==1)?W2:(l==2)?W3:(l==3)?W4:(l==4)?W5:W6;
      float x = (l == 0) ? ((k < 89) ? W[k*128 + sn] : 0.0f)   // K-pad 89->128
                         : W[k*128 + sn];
      v = f2bf(x);
    } else {                                // W7t padded to 32 rows, swizzled
      int o = idx - W7_OFF;
      int n = o >> 7, e = o & 127;
      int k = (((e >> 3) ^ (n & 7)) << 3) | (e & 7);
      int sn = sigma(n);
      v = (sn < 9) ? f2bf(W7[k*9 + sn]) : (unsigned short)0;
    }
    wsb[idx] = v;
  } else if (idx < PREP_N) {                // biases, fp32, sigma-permuted
    int r = idx - WB_N;
    float x;
    if (r < 768) {
      int l = r >> 7, n = r & 127;
      const float* bb = (l==0)?b1:(l==1)?b2:(l==2)?b3:(l==3)?b4:(l==4)?b5:b6;
      x = bb[sigma(n)];
    } else {
      int n = r - 768;
      int sn = sigma(n);
      x = (sn < 9) ? b7[sn] : 0.0f;
    }
    wsf[r] = x;
  }
}

// One tn-pair of the layer MFMA: 2 interleaved acc chains over the K loop.
// Bias rides in as the MFMA C operand at kk==0 (LDS appendix, broadcast).
#define MFMA_PAIR(WPTR, BLS, T0, NKK)                                         \
  UNROLL                                                                      \
  for (int kk = 0; kk < (NKK); ++kk) {                                        \
    bf16x8 x_ = __builtin_bit_cast(bf16x8, xw[kk]);                           \
    const int ch_ = ((2*kk + lk) ^ x7) << 3;                                  \
    UNROLL                                                                    \
    for (int t_ = 0; t_ < 2; ++t_) {                                          \
      const int tn_ = (T0) + t_;                                              \
      bf16x8 w_ = *(const bf16x8*)&(WPTR)[tn_*4096 + rb0 + ch_];              \
      if (kk == 0) {                                                          \
        f32x16 cf_;                                                           \
        UNROLL                                                                \
        for (int qq = 0; qq < 4; ++qq) {                                      \
          f32x4 b4_ = *(const f32x4*)&(BLS)[tn_*32 + qq*8 + lk*4];            \
          cf_[4*qq+0] = b4_[0]; cf_[4*qq+1] = b4_[1];                         \
          cf_[4*qq+2] = b4_[2]; cf_[4*qq+3] = b4_[3];                         \
        }                                                                     \
        acc[tn_] = MFMA(w_, x_, cf_, 0, 0, 0);                                \
      } else {                                                                \
        acc[tn_] = MFMA(w_, x_, acc[tn_], 0, 0, 0);                           \
      }                                                                       \
    }                                                                         \
  }

#define MFMA_LAYER(WPTR, NKK)                                                 \
  {                                                                           \
    const unsigned short* wp_ = (WPTR);                                       \
    const float* bls_ = (const float*)((const char*)wp_ + 32768);             \
    MFMA_PAIR(wp_, bls_, 0, NKK)                                              \
    MFMA_PAIR(wp_, bls_, 2, NKK)                                              \
  }

// GELU + pack: acc slots (pairs within a (tn,q) combo c) -> next-layer B words.
#define GELU_EPILOGUE                                                         \
  UNROLL                                                                      \
  for (int c = 0; c < 16; ++c) {                                              \
    const int tn_ = c >> 2, q_ = c & 3, t_ = c >> 1, h_ = c & 1;              \
    f32x2 za_, zb_;                                                           \
    za_.x = acc[tn_][4*q_+0]; za_.y = acc[tn_][4*q_+1];                       \
    zb_.x = acc[tn_][4*q_+2]; zb_.y = acc[tn_][4*q_+3];                       \
    f32x2 ga_ = gelu2(za_);                                                   \
    f32x2 gb_ = gelu2(zb_);                                                   \
    xw[t_][2*h_ + 0] = pack_bf16(ga_.x, ga_.y);                               \
    xw[t_][2*h_ + 1] = pack_bf16(gb_.x, gb_.y);                               \
  }

// stage a full 32KB weight tile (+512B bias) into LDS buffer, async (512 thr)
#define STAGE_W(LOFF, BUFIDX)                                                 \
  {                                                                           \
    const char* s_ = (const char*)(wst + (LOFF));                             \
    char* d_ = (char*)wbuf[BUFIDX];                                           \
    UNROLL                                                                    \
    for (int i_ = 0; i_ < 4; ++i_)                                            \
      cp16(s_ + i_*8192 + tid*16, d_ + i_*8192 + tid*16);                     \
  }
#define STAGE_B(BOFF, BUFIDX, NT)                                             \
  if (tid < (NT))                                                             \
    cp16((const char*)(wsf + (BOFF)) + tid*16,                                \
         (char*)wbuf[BUFIDX] + 32768 + tid*16);

// ---- main fused kernel: features + 7-layer MLP + symmetrize ----
// Register-resident activations; double-buffered LDS weights: one barrier
// per layer, MFMA and GELU in one straight-line region (pipe overlap).
__global__ __launch_bounds__(512, 4) void stress_mlp(
    const float* __restrict__ F, const float* __restrict__ Cmat,
    const int* __restrict__ traj, const float* __restrict__ latent,
    const unsigned short* __restrict__ wst, const float* __restrict__ wsf,
    float* __restrict__ out)
{
  // 2 x (32KB weights + 512B bias) = 66560 B -> 2 blocks/CU
  __shared__ __align__(16) unsigned short wbuf[2][16384 + 256];

  const int tid  = threadIdx.x;
  const int lane = tid & 63;
  const int wid  = tid >> 6;                  // 0..7
  const int lm   = lane & 31;
  const int lk   = lane >> 5;                 // k-half / n-quad selector
  const int x7   = lm & 7;
  const int rb0  = lm << 7;
  const int pbase = (int)blockIdx.x << 8;     // 256 particles/block
  const int p    = pbase + (wid << 5) + lm;   // both lane-halves: same particle

  // issue W1 + b1 staging immediately (async DMA, overlaps feature phase)
  STAGE_W(0, 0)
  STAGE_B(0, 0, 32)

  u32x4 xw[8];   // B-fragment words; layer 1 uses xw[0..5] (K=96)

  // ---------- features -> layer-1 B words, fully in registers ----------
  {
    const float* Fp = F + (size_t)p * 9;
    float f[9];
    UNROLL
    for (int i = 0; i < 9; ++i) f[i] = Fp[i];
    float fft[9];
    UNROLL
    for (int i = 0; i < 3; ++i)
      UNROLL
      for (int k = 0; k < 3; ++k)
        fft[i*3+k] = f[i*3]*f[k*3] + f[i*3+1]*f[k*3+1] + f[i*3+2]*f[k*3+2];
    const float* lat = latent + (size_t)traj[0] * 64;

    if (lk == 0) {
      // octets 0,2,4,6,8,10: k = {0-7,16-23,32-39,48-55,64-71,80-87}
      xw[0][0] = pack_bf16(fft[0], fft[1]);
      xw[0][1] = pack_bf16(fft[2], fft[3]);
      xw[0][2] = pack_bf16(fft[4], fft[5]);
      xw[0][3] = pack_bf16(fft[6], fft[7]);
      const float* Cp = Cmat + (size_t)p * 9;
      UNROLL
      for (int i = 0; i < 4; ++i) xw[1][i] = pack_bf16(Cp[2*i], Cp[2*i+1]);
      UNROLL
      for (int t = 0; t < 4; ++t) {          // lat[7+16t .. 14+16t]
        const float* lb = lat + 7 + 16*t;
        UNROLL
        for (int i = 0; i < 4; ++i) xw[2+t][i] = pack_bf16(lb[2*i], lb[2*i+1]);
      }
    } else {
      // octets 1,3,5,7,9,11: k = {8-15,24-31,40-47,56-63,72-79,88-95}
      float det = f[0]*(f[4]*f[8]-f[5]*f[7]) - f[1]*(f[3]*f[8]-f[5]*f[6])
                + f[2]*(f[3]*f[7]-f[4]*f[6]);
      float J  = fmaxf(det, 1e-6f);
      float J1 = fmaxf(f[0], 1e-6f);
      // singular values = sqrt(eig(F F^T)); analytic symmetric 3x3 eigensolve
      float a00=fft[0], a01=fft[1], a02=fft[2], a11=fft[4], a12=fft[5], a22=fft[8];
      float q  = (a00+a11+a22) * (1.0f/3.0f);
      float d0 = a00-q, d1 = a11-q, d2 = a22-q;
      float p2 = d0*d0 + d1*d1 + d2*d2 + 2.0f*(a01*a01 + a02*a02 + a12*a12);
      float e0, e1, e2;
      if (p2 < 1e-14f) { e0 = e1 = e2 = q; }
      else {
        float pp  = sqrtf(p2 * (1.0f/6.0f));
        float inv = 1.0f / pp;
        float b00=d0*inv, b11=d1*inv, b22=d2*inv, b01=a01*inv, b02=a02*inv, b12=a12*inv;
        float detb = b00*(b11*b22-b12*b12) - b01*(b01*b22-b12*b02) + b02*(b01*b12-b11*b02);
        float rr = 0.5f * detb;
        rr = fminf(fmaxf(rr, -1.0f), 1.0f);
        float pr = acosf(rr) * (1.0f / (3.0f * 6.2831853071795864f));  // revolutions
        e0 = q + 2.0f*pp*__builtin_amdgcn_cosf(pr);
        e2 = q + 2.0f*pp*__builtin_amdgcn_cosf(pr + (1.0f/3.0f));
        e1 = 3.0f*q - e0 - e2;
      }
      float s0 = sqrtf(fmaxf(e0, 0.f));
      float s1 = sqrtf(fmaxf(e1, 0.f));
      float s2 = sqrtf(fmaxf(e2, 0.f));
      xw[0][0] = pack_bf16(fft[8], logf(J));
      xw[0][1] = pack_bf16(s0, s1);
      xw[0][2] = pack_bf16(s2, J);
      xw[0][3] = pack_bf16(logf(J1), J1);
      float c8 = Cmat[(size_t)p*9 + 8];
      xw[1][0] = pack_bf16(c8, lat[0]);
      xw[1][1] = pack_bf16(lat[1], lat[2]);
      xw[1][2] = pack_bf16(lat[3], lat[4]);
      xw[1][3] = pack_bf16(lat[5], lat[6]);
      UNROLL
      for (int t = 0; t < 3; ++t) {          // lat[15+16t .. 22+16t]
        const float* lb = lat + 15 + 16*t;
        UNROLL
        for (int i = 0; i < 4; ++i) xw[2+t][i] = pack_bf16(lb[2*i], lb[2*i+1]);
      }
      xw[5][0] = pack_bf16(lat[63], 0.0f);   // k88, k89=0
      xw[5][1] = 0u; xw[5][2] = 0u; xw[5][3] = 0u;  // k90-95 = 0
    }
  }

  f32x16 acc[4];

  // schedule: bar; stage W(l+1)->other; MFMA(l)+GELU(l); bar; ...
  __syncthreads();                 // W1 staged (vmcnt drained at barrier)
  STAGE_W(1 << 14, 1) STAGE_B(128, 1, 32)
  MFMA_LAYER(wbuf[0], 6)           // layer 1, K=96
  GELU_EPILOGUE
  __syncthreads();                 // W2 staged; wbuf[0] reads done

  STAGE_W(2 << 14, 0) STAGE_B(256, 0, 32)
  MFMA_LAYER(wbuf[1], 8)           // layer 2
  GELU_EPILOGUE
  __syncthreads();

  STAGE_W(3 << 14, 1) STAGE_B(384, 1, 32)
  MFMA_LAYER(wbuf[0], 8)           // layer 3
  GELU_EPILOGUE
  __syncthreads();

  STAGE_W(4 << 14, 0) STAGE_B(512, 0, 32)
  MFMA_LAYER(wbuf[1], 8)           // layer 4
  GELU_EPILOGUE
  __syncthreads();

  STAGE_W(5 << 14, 1) STAGE_B(640, 1, 32)
  MFMA_LAYER(wbuf[0], 8)           // layer 5
  GELU_EPILOGUE
  __syncthreads();

  {                                // stage W7 (8KB) + b7 into buf 0
    const char* s_ = (const char*)(wst + W7_OFF);
    cp16(s_ + tid*16, (char*)wbuf[0] + tid*16);   // 512*16 = 8192 B
    STAGE_B(768, 0, 8)
  }
  MFMA_LAYER(wbuf[1], 8)           // layer 6
  GELU_EPILOGUE
  __syncthreads();                 // W7 staged; wbuf[1] reads done

  // ---------- layer 7 (128 -> 9, no activation) + symmetrize ----------
  f32x16 a7;
  {
    const unsigned short* wp = wbuf[0];
    const float* bls = (const float*)((const char*)wp + 32768);
    UNROLL
    for (int kk = 0; kk < 8; ++kk) {
      bf16x8 x = __builtin_bit_cast(bf16x8, xw[kk]);
      const int ch = ((2*kk + lk) ^ x7) << 3;
      bf16x8 w = *(const bf16x8*)&wp[rb0 + ch];
      if (kk == 0) {
        f32x16 cf;
        UNROLL
        for (int qq = 0; qq < 4; ++qq) {
          f32x4 b4 = *(const f32x4*)&bls[qq*8 + lk*4];
          cf[4*qq+0] = b4[0]; cf[4*qq+1] = b4[1];
          cf[4*qq+2] = b4[2]; cf[4*qq+3] = b4[3];
        }
        a7 = MFMA(w, x, cf, 0, 0, 0);
      } else {
        a7 = MFMA(w, x, a7, 0, 0, 0);
      }
    }
  }

  // slot->real output (sigma): lower lanes hold o0..o7 in regs 0..7,
  // o8 sits in upper-lane reg 0 -> one cross-half shuffle.
  float o8 = __shfl_xor(a7[0], 32);
  float* ots = (float*)wbuf[1];    // [256][9] fp32 scratch (wbuf[1] free now)
  if (lk == 0) {
    const int row = (wid << 5) + lm;
    float z[9];
    UNROLL
    for (int i = 0; i < 8; ++i) z[i] = a7[i];
    z[8] = o8;
    UNROLL
    for (int rr = 0; rr < 3; ++rr)
      UNROLL
      for (int cc = 0; cc < 3; ++cc)
        ots[row*9 + rr*3 + cc] = 0.5f * (z[rr*3+cc] + z[cc*3+rr]);
  }
  __syncthreads();

  float4* dst = (float4*)(out + (size_t)pbase * 9);   // 9216 B, 16B-aligned
  const float4* srcv = (const float4*)ots;
  UNROLL
  for (int s = tid; s < 576; s += 512) dst[s] = srcv[s];
}

extern "C" void kernel_launch(void* const* d_in, const int* in_sizes, int n_in,
                              void* d_out, int out_size, void* d_ws, size_t ws_size,
                              hipStream_t stream) {
  const float* F   = (const float*)d_in[0];
  const float* C   = (const float*)d_in[1];
  const int*   trj = (const int*)d_in[2];
  const float* lat = (const float*)d_in[3];
  const float* W1  = (const float*)d_in[4];
  const float* b1  = (const float*)d_in[5];
  const float* W2  = (const float*)d_in[6];
  const float* b2  = (const float*)d_in[7];
  const float* W3  = (const float*)d_in[8];
  const float* b3  = (const float*)d_in[9];
  const float* W4  = (const float*)d_in[10];
  const float* b4  = (const float*)d_in[11];
  const float* W5  = (const float*)d_in[12];
  const float* b5  = (const float*)d_in[13];
  const float* W6  = (const float*)d_in[14];
  const float* b6  = (const float*)d_in[15];
  const float* W7  = (const float*)d_in[16];
  const float* b7  = (const float*)d_in[17];

  unsigned short* wsb = (unsigned short*)d_ws;           // bf16 swizzled Wt image
  float* wsf = (float*)((char*)d_ws + WB_N * 2);         // fp32 biases (16B-aligned)

  prep_weights<<<dim3((PREP_N + 255) / 256), dim3(256), 0, stream>>>(
      W1, W2, W3, W4, W5, W6, W7, b1, b2, b3, b4, b5, b6, b7, wsb, wsf);
  stress_mlp<<<dim3(NBLK), dim3(512), 0, stream>>>(
      F, C, trj, lat, wsb, wsf, (float*)d_out);
}

// Round 8
// 257.409 us; speedup vs baseline: 1.2086x; 1.2086x over previous
//
#include <hip/hip_runtime.h>
#include <hip/hip_bf16.h>
#include <math.h>

// Problem constants
#define BPART   524288
#define NBLK    (BPART / 256)  // 2048 blocks x 256 particles (8 waves x 32)
#define W7_OFF  98304          // 6 * 16384 bf16
#define WB_N    102400         // + 32*128 (padded W7t), bf16 count
#define BIAS_N  800            // 6*128 + 32 floats
#define PREP_N  (WB_N + BIAS_N)

typedef __bf16 bf16x8 __attribute__((ext_vector_type(8)));
typedef float  f32x16 __attribute__((ext_vector_type(16)));
typedef float  f32x4  __attribute__((ext_vector_type(4)));
typedef float  f32x2  __attribute__((ext_vector_type(2)));
typedef unsigned u32x4 __attribute__((ext_vector_type(4)));

#define MFMA __builtin_amdgcn_mfma_f32_32x32x16_bf16
#define UNROLL _Pragma("unroll")

__device__ __forceinline__ unsigned short f2bf(float f) {
  union { float f; unsigned u; } v; v.f = f;
  unsigned r = v.u + 0x7fffu + ((v.u >> 16) & 1u);   // RNE
  return (unsigned short)(r >> 16);
}
// pack two fp32 -> bf16x2 (low16 = a, high16 = b), explicit RNE — verified.
// (v_cvt_pk_bf16_f32 regressed absmax 7.8e-3 -> 4.2e-2 in R4: not RNE. Do
// not substitute it. R6's poly-sigmoid tail: +5 VALU slots, 183->236. R7's
// pk_add/pk_mul gelu restructure + setprio produced NaN; gelu kept VERBATIM
// from R2 here.)
__device__ __forceinline__ unsigned pack_bf16(float a, float b) {
  unsigned ua = __builtin_bit_cast(unsigned, a) + 0x8000u;
  unsigned ub = __builtin_bit_cast(unsigned, b) + 0x8000u;
  return __builtin_amdgcn_perm(ub, ua, 0x07060302u);
}

// sigma: D-slot index -> real feature index. With weight rows (and biases)
// stored permuted by sigma, the MFMA D layout (n = 32tn+8q+4lk+j per lane)
// becomes, after pairwise bf16 packing, EXACTLY the next layer's B-fragment
// layout (k = 16t+8lk+4h+j, t=c>>1, h=c&1, c=4tn+q). Bijective bit shuffle.
__device__ __forceinline__ int sigma(int n) {
  int c = ((n >> 5) << 2) | ((n >> 3) & 3);
  return ((c >> 1) << 4) | (((n >> 2) & 1) << 3) | ((c & 1) << 2) | (n & 3);
}

// packed fp32 VALU (VOP3P)
__device__ __forceinline__ f32x2 pk_mul(f32x2 a, f32x2 b) {
  f32x2 d; asm("v_pk_mul_f32 %0, %1, %2" : "=v"(d) : "v"(a), "v"(b)); return d;
}
__device__ __forceinline__ f32x2 pk_fma(f32x2 a, f32x2 b, f32x2 c) {
  f32x2 d; asm("v_pk_fma_f32 %0, %1, %2, %3" : "=v"(d) : "v"(a), "v"(b), "v"(c)); return d;
}
// tanh-form GELU on a pair; poly part packed, transcendentals scalar.
// R2-verified form — do not restructure (see history note above).
__device__ __forceinline__ f32x2 gelu2(f32x2 z) {
  const f32x2 c1 = {0.1029432f, 0.1029432f};
  const f32x2 c0 = {2.30220818f, 2.30220818f};
  f32x2 z2 = pk_mul(z, z);
  f32x2 t  = pk_fma(z2, c1, c0);
  f32x2 yp = pk_mul(z, t);
  float e0 = __builtin_amdgcn_exp2f(-yp.x);
  float e1 = __builtin_amdgcn_exp2f(-yp.y);
  float r0 = __builtin_amdgcn_rcpf(e0 + 1.0f);
  float r1 = __builtin_amdgcn_rcpf(e1 + 1.0f);
  f32x2 g; g.x = z.x * r0; g.y = z.y * r1;
  return g;
}
// async 16B global->LDS (lane-linear dest)
__device__ __forceinline__ void cp16(const void* g, void* l) {
  __builtin_amdgcn_global_load_lds(
      (const __attribute__((address_space(1))) void*)g,
      (__attribute__((address_space(3))) void*)l, 16, 0, 0);
}

// ---- prep: cast+transpose fp32 weights into d_ws as the EXACT swizzled
// LDS image, with rows sigma-permuted (see sigma()). Biases permuted too. ----
__global__ void prep_weights(
    const float* __restrict__ W1, const float* __restrict__ W2,
    const float* __restrict__ W3, const float* __restrict__ W4,
    const float* __restrict__ W5, const float* __restrict__ W6,
    const float* __restrict__ W7,
    const float* __restrict__ b1, const float* __restrict__ b2,
    const float* __restrict__ b3, const float* __restrict__ b4,
    const float* __restrict__ b5, const float* __restrict__ b6,
    const float* __restrict__ b7,
    unsigned short* __restrict__ wsb, float* __restrict__ wsf)
{
  int idx = blockIdx.x * 256 + threadIdx.x;
  if (idx < WB_N) {
    unsigned short v = 0;
    if (idx < W7_OFF) {                     // W1..W6: Wt[sigma(n)][k] swizzled
      int l = idx >> 14;
      int o = idx & 16383;
      int n = o >> 7, e = o & 127;
      int k = (((e >> 3) ^ (n & 7)) << 3) | (e & 7);
      int sn = sigma(n);
      const float* W = (l==0)?W1:(l==1)?W2:(l==2)?W3:(l==3)?W4:(l==4)?W5:W6;
      float x = (l == 0) ? ((k < 89) ? W[k*128 + sn] : 0.0f)   // K-pad 89->128
                         : W[k*128 + sn];
      v = f2bf(x);
    } else {                                // W7t padded to 32 rows, swizzled
      int o = idx - W7_OFF;
      int n = o >> 7, e = o & 127;
      int k = (((e >> 3) ^ (n & 7)) << 3) | (e & 7);
      int sn = sigma(n);
      v = (sn < 9) ? f2bf(W7[k*9 + sn]) : (unsigned short)0;
    }
    wsb[idx] = v;
  } else if (idx < PREP_N) {                // biases, fp32, sigma-permuted
    int r = idx - WB_N;
    float x;
    if (r < 768) {
      int l = r >> 7, n = r & 127;
      const float* bb = (l==0)?b1:(l==1)?b2:(l==2)?b3:(l==3)?b4:(l==4)?b5:b6;
      x = bb[sigma(n)];
    } else {
      int n = r - 768;
      int sn = sigma(n);
      x = (sn < 9) ? b7[sn] : 0.0f;
    }
    wsf[r] = x;
  }
}

// One tn-pair of the layer MFMA: 2 interleaved acc chains over the K loop.
// Bias rides in as the MFMA C operand at kk==0 (LDS appendix, broadcast).
#define MFMA_PAIR(WPTR, BLS, T0, NKK)                                         \
  UNROLL                                                                      \
  for (int kk = 0; kk < (NKK); ++kk) {                                        \
    bf16x8 x_ = __builtin_bit_cast(bf16x8, xw[kk]);                           \
    const int ch_ = ((2*kk + lk) ^ x7) << 3;                                  \
    UNROLL                                                                    \
    for (int t_ = 0; t_ < 2; ++t_) {                                          \
      const int tn_ = (T0) + t_;                                              \
      bf16x8 w_ = *(const bf16x8*)&(WPTR)[tn_*4096 + rb0 + ch_];              \
      if (kk == 0) {                                                          \
        f32x16 cf_;                                                           \
        UNROLL                                                                \
        for (int qq = 0; qq < 4; ++qq) {                                      \
          f32x4 b4_ = *(const f32x4*)&(BLS)[tn_*32 + qq*8 + lk*4];            \
          cf_[4*qq+0] = b4_[0]; cf_[4*qq+1] = b4_[1];                         \
          cf_[4*qq+2] = b4_[2]; cf_[4*qq+3] = b4_[3];                         \
        }                                                                     \
        acc[tn_] = MFMA(w_, x_, cf_, 0, 0, 0);                                \
      } else {                                                                \
        acc[tn_] = MFMA(w_, x_, acc[tn_], 0, 0, 0);                           \
      }                                                                       \
    }                                                                         \
  }

// T5 (single-variable vs R2): setprio(1) around the MFMA cluster — waves in
// their MFMA phase win CU-scheduler arbitration over waves in their GELU
// phase, packing the matrix pipe; GELU waves fill VALU gaps at prio 0.
#define MFMA_LAYER(WPTR, NKK)                                                 \
  {                                                                           \
    const unsigned short* wp_ = (WPTR);                                       \
    const float* bls_ = (const float*)((const char*)wp_ + 32768);             \
    __builtin_amdgcn_s_setprio(1);                                            \
    MFMA_PAIR(wp_, bls_, 0, NKK)                                              \
    MFMA_PAIR(wp_, bls_, 2, NKK)                                              \
    __builtin_amdgcn_s_setprio(0);                                            \
  }

// GELU + pack: acc slots (pairs within a (tn,q) combo c) -> next-layer B words.
#define GELU_EPILOGUE                                                         \
  UNROLL                                                                      \
  for (int c = 0; c < 16; ++c) {                                              \
    const int tn_ = c >> 2, q_ = c & 3, t_ = c >> 1, h_ = c & 1;              \
    f32x2 za_, zb_;                                                           \
    za_.x = acc[tn_][4*q_+0]; za_.y = acc[tn_][4*q_+1];                       \
    zb_.x = acc[tn_][4*q_+2]; zb_.y = acc[tn_][4*q_+3];                       \
    f32x2 ga_ = gelu2(za_);                                                   \
    f32x2 gb_ = gelu2(zb_);                                                   \
    xw[t_][2*h_ + 0] = pack_bf16(ga_.x, ga_.y);                               \
    xw[t_][2*h_ + 1] = pack_bf16(gb_.x, gb_.y);                               \
  }

// stage a full 32KB weight tile (+512B bias) into LDS buffer, async (512 thr)
#define STAGE_W(LOFF, BUFIDX)                                                 \
  {                                                                           \
    const char* s_ = (const char*)(wst + (LOFF));                             \
    char* d_ = (char*)wbuf[BUFIDX];                                           \
    UNROLL                                                                    \
    for (int i_ = 0; i_ < 4; ++i_)                                            \
      cp16(s_ + i_*8192 + tid*16, d_ + i_*8192 + tid*16);                     \
  }
#define STAGE_B(BOFF, BUFIDX, NT)                                             \
  if (tid < (NT))                                                             \
    cp16((const char*)(wsf + (BOFF)) + tid*16,                                \
         (char*)wbuf[BUFIDX] + 32768 + tid*16);

// ---- main fused kernel: features + 7-layer MLP + symmetrize ----
// Register-resident activations; double-buffered LDS weights: one barrier
// per layer, MFMA and GELU in one straight-line region (pipe overlap).
__global__ __launch_bounds__(512, 4) void stress_mlp(
    const float* __restrict__ F, const float* __restrict__ Cmat,
    const int* __restrict__ traj, const float* __restrict__ latent,
    const unsigned short* __restrict__ wst, const float* __restrict__ wsf,
    float* __restrict__ out)
{
  // 2 x (32KB weights + 512B bias) = 66560 B -> 2 blocks/CU
  __shared__ __align__(16) unsigned short wbuf[2][16384 + 256];

  const int tid  = threadIdx.x;
  const int lane = tid & 63;
  const int wid  = tid >> 6;                  // 0..7
  const int lm   = lane & 31;
  const int lk   = lane >> 5;                 // k-half / n-quad selector
  const int x7   = lm & 7;
  const int rb0  = lm << 7;
  const int pbase = (int)blockIdx.x << 8;     // 256 particles/block
  const int p    = pbase + (wid << 5) + lm;   // both lane-halves: same particle

  // issue W1 + b1 staging immediately (async DMA, overlaps feature phase)
  STAGE_W(0, 0)
  STAGE_B(0, 0, 32)

  u32x4 xw[8];   // B-fragment words; layer 1 uses xw[0..5] (K=96)

  // ---------- features -> layer-1 B words, fully in registers ----------
  {
    const float* Fp = F + (size_t)p * 9;
    float f[9];
    UNROLL
    for (int i = 0; i < 9; ++i) f[i] = Fp[i];
    float fft[9];
    UNROLL
    for (int i = 0; i < 3; ++i)
      UNROLL
      for (int k = 0; k < 3; ++k)
        fft[i*3+k] = f[i*3]*f[k*3] + f[i*3+1]*f[k*3+1] + f[i*3+2]*f[k*3+2];
    const float* lat = latent + (size_t)traj[0] * 64;

    if (lk == 0) {
      // octets 0,2,4,6,8,10: k = {0-7,16-23,32-39,48-55,64-71,80-87}
      xw[0][0] = pack_bf16(fft[0], fft[1]);
      xw[0][1] = pack_bf16(fft[2], fft[3]);
      xw[0][2] = pack_bf16(fft[4], fft[5]);
      xw[0][3] = pack_bf16(fft[6], fft[7]);
      const float* Cp = Cmat + (size_t)p * 9;
      UNROLL
      for (int i = 0; i < 4; ++i) xw[1][i] = pack_bf16(Cp[2*i], Cp[2*i+1]);
      UNROLL
      for (int t = 0; t < 4; ++t) {          // lat[7+16t .. 14+16t]
        const float* lb = lat + 7 + 16*t;
        UNROLL
        for (int i = 0; i < 4; ++i) xw[2+t][i] = pack_bf16(lb[2*i], lb[2*i+1]);
      }
    } else {
      // octets 1,3,5,7,9,11: k = {8-15,24-31,40-47,56-63,72-79,88-95}
      float det = f[0]*(f[4]*f[8]-f[5]*f[7]) - f[1]*(f[3]*f[8]-f[5]*f[6])
                + f[2]*(f[3]*f[7]-f[4]*f[6]);
      float J  = fmaxf(det, 1e-6f);
      float J1 = fmaxf(f[0], 1e-6f);
      // singular values = sqrt(eig(F F^T)); analytic symmetric 3x3 eigensolve
      float a00=fft[0], a01=fft[1], a02=fft[2], a11=fft[4], a12=fft[5], a22=fft[8];
      float q  = (a00+a11+a22) * (1.0f/3.0f);
      float d0 = a00-q, d1 = a11-q, d2 = a22-q;
      float p2 = d0*d0 + d1*d1 + d2*d2 + 2.0f*(a01*a01 + a02*a02 + a12*a12);
      float e0, e1, e2;
      if (p2 < 1e-14f) { e0 = e1 = e2 = q; }
      else {
        float pp  = sqrtf(p2 * (1.0f/6.0f));
        float inv = 1.0f / pp;
        float b00=d0*inv, b11=d1*inv, b22=d2*inv, b01=a01*inv, b02=a02*inv, b12=a12*inv;
        float detb = b00*(b11*b22-b12*b12) - b01*(b01*b22-b12*b02) + b02*(b01*b12-b11*b02);
        float rr = 0.5f * detb;
        rr = fminf(fmaxf(rr, -1.0f), 1.0f);
        float pr = acosf(rr) * (1.0f / (3.0f * 6.2831853071795864f));  // revolutions
        e0 = q + 2.0f*pp*__builtin_amdgcn_cosf(pr);
        e2 = q + 2.0f*pp*__builtin_amdgcn_cosf(pr + (1.0f/3.0f));
        e1 = 3.0f*q - e0 - e2;
      }
      float s0 = sqrtf(fmaxf(e0, 0.f));
      float s1 = sqrtf(fmaxf(e1, 0.f));
      float s2 = sqrtf(fmaxf(e2, 0.f));
      xw[0][0] = pack_bf16(fft[8], logf(J));
      xw[0][1] = pack_bf16(s0, s1);
      xw[0][2] = pack_bf16(s2, J);
      xw[0][3] = pack_bf16(logf(J1), J1);
      float c8 = Cmat[(size_t)p*9 + 8];
      xw[1][0] = pack_bf16(c8, lat[0]);
      xw[1][1] = pack_bf16(lat[1], lat[2]);
      xw[1][2] = pack_bf16(lat[3], lat[4]);
      xw[1][3] = pack_bf16(lat[5], lat[6]);
      UNROLL
      for (int t = 0; t < 3; ++t) {          // lat[15+16t .. 22+16t]
        const float* lb = lat + 15 + 16*t;
        UNROLL
        for (int i = 0; i < 4; ++i) xw[2+t][i] = pack_bf16(lb[2*i], lb[2*i+1]);
      }
      xw[5][0] = pack_bf16(lat[63], 0.0f);   // k88, k89=0
      xw[5][1] = 0u; xw[5][2] = 0u; xw[5][3] = 0u;  // k90-95 = 0
    }
  }

  f32x16 acc[4];

  // schedule: bar; stage W(l+1)->other; MFMA(l)+GELU(l); bar; ...
  __syncthreads();                 // W1 staged (vmcnt drained at barrier)
  STAGE_W(1 << 14, 1) STAGE_B(128, 1, 32)
  MFMA_LAYER(wbuf[0], 6)           // layer 1, K=96
  GELU_EPILOGUE
  __syncthreads();                 // W2 staged; wbuf[0] reads done

  STAGE_W(2 << 14, 0) STAGE_B(256, 0, 32)
  MFMA_LAYER(wbuf[1], 8)           // layer 2
  GELU_EPILOGUE
  __syncthreads();

  STAGE_W(3 << 14, 1) STAGE_B(384, 1, 32)
  MFMA_LAYER(wbuf[0], 8)           // layer 3
  GELU_EPILOGUE
  __syncthreads();

  STAGE_W(4 << 14, 0) STAGE_B(512, 0, 32)
  MFMA_LAYER(wbuf[1], 8)           // layer 4
  GELU_EPILOGUE
  __syncthreads();

  STAGE_W(5 << 14, 1) STAGE_B(640, 1, 32)
  MFMA_LAYER(wbuf[0], 8)           // layer 5
  GELU_EPILOGUE
  __syncthreads();

  {                                // stage W7 (8KB) + b7 into buf 0
    const char* s_ = (const char*)(wst + W7_OFF);
    cp16(s_ + tid*16, (char*)wbuf[0] + tid*16);   // 512*16 = 8192 B
    STAGE_B(768, 0, 8)
  }
  MFMA_LAYER(wbuf[1], 8)           // layer 6
  GELU_EPILOGUE
  __syncthreads();                 // W7 staged; wbuf[1] reads done

  // ---------- layer 7 (128 -> 9, no activation) + symmetrize ----------
  f32x16 a7;
  {
    const unsigned short* wp = wbuf[0];
    const float* bls = (const float*)((const char*)wp + 32768);
    __builtin_amdgcn_s_setprio(1);
    UNROLL
    for (int kk = 0; kk < 8; ++kk) {
      bf16x8 x = __builtin_bit_cast(bf16x8, xw[kk]);
      const int ch = ((2*kk + lk) ^ x7) << 3;
      bf16x8 w = *(const bf16x8*)&wp[rb0 + ch];
      if (kk == 0) {
        f32x16 cf;
        UNROLL
        for (int qq = 0; qq < 4; ++qq) {
          f32x4 b4 = *(const f32x4*)&bls[qq*8 + lk*4];
          cf[4*qq+0] = b4[0]; cf[4*qq+1] = b4[1];
          cf[4*qq+2] = b4[2]; cf[4*qq+3] = b4[3];
        }
        a7 = MFMA(w, x, cf, 0, 0, 0);
      } else {
        a7 = MFMA(w, x, a7, 0, 0, 0);
      }
    }
    __builtin_amdgcn_s_setprio(0);
  }

  // slot->real output (sigma): lower lanes hold o0..o7 in regs 0..7,
  // o8 sits in upper-lane reg 0 -> one cross-half shuffle.
  float o8 = __shfl_xor(a7[0], 32);
  float* ots = (float*)wbuf[1];    // [256][9] fp32 scratch (wbuf[1] free now)
  if (lk == 0) {
    const int row = (wid << 5) + lm;
    float z[9];
    UNROLL
    for (int i = 0; i < 8; ++i) z[i] = a7[i];
    z[8] = o8;
    UNROLL
    for (int rr = 0; rr < 3; ++rr)
      UNROLL
      for (int cc = 0; cc < 3; ++cc)
        ots[row*9 + rr*3 + cc] = 0.5f * (z[rr*3+cc] + z[cc*3+rr]);
  }
  __syncthreads();

  float4* dst = (float4*)(out + (size_t)pbase * 9);   // 9216 B, 16B-aligned
  const float4* srcv = (const float4*)ots;
  UNROLL
  for (int s = tid; s < 576; s += 512) dst[s] = srcv[s];
}

extern "C" void kernel_launch(void* const* d_in, const int* in_sizes, int n_in,
                              void* d_out, int out_size, void* d_ws, size_t ws_size,
                              hipStream_t stream) {
  const float* F   = (const float*)d_in[0];
  const float* C   = (const float*)d_in[1];
  const int*   trj = (const int*)d_in[2];
  const float* lat = (const float*)d_in[3];
  const float* W1  = (const float*)d_in[4];
  const float* b1  = (const float*)d_in[5];
  const float* W2  = (const float*)d_in[6];
  const float* b2  = (const float*)d_in[7];
  const float* W3  = (const float*)d_in[8];
  const float* b3  = (const float*)d_in[9];
  const float* W4  = (const float*)d_in[10];
  const float* b4  = (const float*)d_in[11];
  const float* W5  = (const float*)d_in[12];
  const float* b5  = (const float*)d_in[13];
  const float* W6  = (const float*)d_in[14];
  const float* b6  = (const float*)d_in[15];
  const float* W7  = (const float*)d_in[16];
  const float* b7  = (const float*)d_in[17];

  unsigned short* wsb = (unsigned short*)d_ws;           // bf16 swizzled Wt image
  float* wsf = (float*)((char*)d_ws + WB_N * 2);         // fp32 biases (16B-aligned)

  prep_weights<<<dim3((PREP_N + 255) / 256), dim3(256), 0, stream>>>(
      W1, W2, W3, W4, W5, W6, W7, b1, b2, b3, b4, b5, b6, b7, wsb, wsf);
  stress_mlp<<<dim3(NBLK), dim3(512), 0, stream>>>(
      F, C, trj, lat, wsb, wsf, (float*)d_out);
}